// Round 5
// baseline (40.270 us; speedup 1.0000x reference)
//
#include <hip/hip_runtime.h>
#include <math.h>

#define NN 128
#define MLINKS 256
#define KK 5
#define HID 128
#define EF 17
#define BATCH 16
#define IN_DIM 86721
#define COMB 33089
#define NBLK2 259                  // ceil(33089/128)

// input-row offsets
#define OFF_SD 0
#define OFF_SLOTS 256
#define OFF_SPEC 261
#define OFF_LF 321
#define OFF_BET 4673
#define OFF_ADJ 4801

// concat layout: [0,16384) Hm | then ck = k-16384:
//   [0,256) SD | [256,261) slots | [261,291) c_band | [291,321) l_band |
//   [321, 321+16384) alpha (a = ck-321, row i = a>>7, col j = a&127)

__device__ __forceinline__ float fast_tanh(float x) {
    x = fminf(fmaxf(x, -15.f), 15.f);
    const float e = __expf(2.f * x);
    return (e - 1.f) / (e + 1.f);
}

__device__ __forceinline__ float wsum(float v) {
    #pragma unroll
    for (int d = 1; d < 64; d <<= 1) v += __shfl_xor(v, d);
    return v;
}

// small-feature gather for ck in [0, 321)
__device__ __forceinline__ float gather_tail(const float* __restrict__ row, int ck) {
    if (ck < 256) return row[OFF_SD + ck];
    if (ck < 261) return row[OFF_SLOTS + ck - 256];
    if (ck < 291) { const int t = ck - 261; return row[OFF_SPEC + (t / 6) * 12 + (t % 6)]; }
    const int t = ck - 291; return row[OFF_SPEC + (t / 6) * 12 + 6 + (t % 6)];
}

// ---------------------------------------------------------------------------
// Kernel 1: per-batch scalars. 16 blocks x 256 threads.
// scal[b*4 + {0,1,2,3}] = {d1, d2, se, ec0}
// ---------------------------------------------------------------------------
__global__ __launch_bounds__(256) void k_pre(const float* __restrict__ in,
                                             const float* __restrict__ WH,
                                             const float* __restrict__ WE,
                                             const float* __restrict__ a_attn,
                                             float* __restrict__ scal) {
    const int b = blockIdx.x;
    const int tid = threadIdx.x;
    const float* row = in + (size_t)b * IN_DIM;

    __shared__ float lf_lds[MLINKS * EF];
    __shared__ float lfp[EF][8];
    __shared__ float lfm[EF];
    __shared__ float red0[HID], red1[HID], red2[HID];

    for (int i = tid; i < MLINKS * EF; i += 256) lf_lds[i] = row[OFF_LF + i];
    __syncthreads();
    if (tid < EF * 8) {
        const int e = tid >> 3, c = tid & 7;
        float s = 0.f;
        #pragma unroll 8
        for (int m = c; m < MLINKS; m += 8) s += lf_lds[m * EF + e];
        lfp[e][c] = s;
    }
    __syncthreads();
    if (tid < EF) {
        lfm[tid] = (((lfp[tid][0] + lfp[tid][1]) + (lfp[tid][2] + lfp[tid][3]))
                  + ((lfp[tid][4] + lfp[tid][5]) + (lfp[tid][6] + lfp[tid][7])))
                 * (1.0f / 256.0f);
    }
    __syncthreads();
    if (tid < HID) {
        float ecv = 0.f;
        #pragma unroll
        for (int e = 0; e < EF; ++e) ecv += lfm[e] * WE[e * HID + tid];
        const float wh = WH[tid];
        red0[tid] = wh * a_attn[tid];
        red1[tid] = wh * a_attn[HID + tid];
        red2[tid] = ecv * a_attn[2 * HID + tid];
        if (tid == 0) scal[b * 4 + 3] = ecv;   // ec0
    }
    __syncthreads();
    for (int s = 64; s > 0; s >>= 1) {
        if (tid < s) {
            red0[tid] += red0[tid + s];
            red1[tid] += red1[tid + s];
            red2[tid] += red2[tid + s];
        }
        __syncthreads();
    }
    if (tid == 0) {
        scal[b * 4 + 0] = red0[0];
        scal[b * 4 + 1] = red1[0];
        scal[b * 4 + 2] = red2[0];
    }
}

// ---------------------------------------------------------------------------
// Kernel 2: fused x-tile synthesis + split-K GEMM. 259 blocks x 512 threads.
// Block p synthesizes x[:, p*128 : p*128+128] in LDS:
//   p < 128   : softmax row p (all 16 batches) -> sab; tile = sab * WH  (rank-1 Hm)
//   p in 128..130: gather SD/slots/bands directly from input (+ alpha row 0 tail)
//   p >= 130  : compute the 1-2 straddled alpha rows' softmax, write normalized
// Then k-split-2 GEMM vs W0 into its own partial slab (deterministic).
// ---------------------------------------------------------------------------
__global__ __launch_bounds__(512) void k_main(const float* __restrict__ in,
                                              const float* __restrict__ scal,
                                              const float* __restrict__ WH,
                                              const float* __restrict__ W0,
                                              const float* __restrict__ Wr,
                                              float* __restrict__ part) {
    const int p = blockIdx.x;
    const int tid = threadIdx.x;
    const int wv = tid >> 6, lane = tid & 63;

    __shared__ float xs[BATCH][128];
    __shared__ float bet_s[BATCH][128];
    __shared__ float scal_s[BATCH][4];
    __shared__ float WH_s[HID];
    __shared__ float sab16[BATCH];
    __shared__ float4 redA[256];
    __shared__ float4 redB[256];

    // stage per-batch scalars + betweenness (16x128) + WH
    if (tid < 64) scal_s[tid >> 2][tid & 3] = scal[tid];
    for (int i = tid; i < BATCH * 128; i += 512)
        bet_s[i >> 7][i & 127] = in[(size_t)(i >> 7) * IN_DIM + OFF_BET + (i & 127)];
    if (p < 128 && tid >= 128 && tid < 256) WH_s[tid - 128] = WH[tid - 128];

    // prefetch Wr (256 KB) into L2/L3 so k_tail isn't HBM-cold
    {
        const int pidx = p * 512 + tid;
        if (pidx < 16384) {
            const float4 wp = reinterpret_cast<const float4*>(Wr)[pidx];
            asm volatile("" :: "v"(wp.x), "v"(wp.y), "v"(wp.z), "v"(wp.w));
        }
    }
    __syncthreads();

    if (p < 128) {
        // wave w: softmax row p for batches 2w, 2w+1 -> sab16[b]
        #pragma unroll
        for (int rb = 0; rb < 2; ++rb) {
            const int b = wv * 2 + rb;
            const float d1 = scal_s[b][0], d2 = scal_s[b][1];
            const float se = scal_s[b][2], ec0 = scal_s[b][3];
            const float* row = in + (size_t)b * IN_DIM;
            const float betA = bet_s[b][lane], betB = bet_s[b][lane + 64];
            const float sq = bet_s[b][p] * d1 + se;
            const float adj1 = row[OFF_ADJ + p * NN + lane];
            const float adj2 = row[OFF_ADJ + p * NN + 64 + lane];
            float e1 = (adj1 > 0.f) ? __expf(fast_tanh(sq + betA * d2)) : 0.f;
            float e2 = (adj2 > 0.f) ? __expf(fast_tanh(sq + betB * d2)) : 0.f;
            const float s  = wsum(e1 + e2);
            float sb = wsum(e1 * betA + e2 * betB);
            float sab;
            if (s > 0.f) sab = ec0 * sb / s;
            else         sab = ec0 * wsum(betA + betB) * (1.0f / 128.0f);
            if (lane == 0) sab16[b] = sab;
        }
        __syncthreads();
        for (int i = tid; i < BATCH * 128; i += 512)
            xs[i >> 7][i & 127] = sab16[i >> 7] * WH_s[i & 127];
    } else {
        const int base = p * 128 - 16705;        // alpha flat index of kk=0 (signed)

        if (p == NBLK2 - 1) {                    // zero-pad beyond COMB
            for (int i = tid; i < BATCH * 128; i += 512) xs[i >> 7][i & 127] = 0.f;
            __syncthreads();
        }
        if (p <= 130) {                          // gather SD/slots/bands portion
            const int ck0 = p * 128 - 16384;
            for (int i = tid; i < BATCH * 128; i += 512) {
                const int b = i >> 7, kk = i & 127, ck = ck0 + kk;
                if (ck < 321)
                    xs[b][kk] = gather_tail(in + (size_t)b * IN_DIM, ck);
            }
        }
        // alpha rows straddled by this window
        const int a_lo = (base > 0) ? base : 0;
        const int a_hi = (base + 128 < 16384) ? base + 128 : 16384;  // exclusive
        if (a_lo < a_hi) {
            const int r_lo = a_lo >> 7;
            const int r_hi = (a_hi - 1) >> 7;
            const int ntasks = (r_hi - r_lo + 1) * 16;
            for (int t = wv; t < ntasks; t += 8) {
                const int b = t & 15, i = r_lo + (t >> 4);
                const float d1 = scal_s[b][0], d2 = scal_s[b][1], se = scal_s[b][2];
                const float* row = in + (size_t)b * IN_DIM;
                const float betA = bet_s[b][lane], betB = bet_s[b][lane + 64];
                const float sq = bet_s[b][i] * d1 + se;
                const float adj1 = row[OFF_ADJ + i * NN + lane];
                const float adj2 = row[OFF_ADJ + i * NN + 64 + lane];
                float e1 = (adj1 > 0.f) ? __expf(fast_tanh(sq + betA * d2)) : 0.f;
                float e2 = (adj2 > 0.f) ? __expf(fast_tanh(sq + betB * d2)) : 0.f;
                const float s = wsum(e1 + e2);
                float inv;
                if (s > 0.f) inv = 1.0f / s;
                else { e1 = 1.f; e2 = 1.f; inv = 1.0f / 128.0f; }
                const int kk1 = i * 128 + lane - base;
                const int kk2 = kk1 + 64;
                if (kk1 >= 0 && kk1 < 128) xs[b][kk1] = e1 * inv;
                if (kk2 >= 0 && kk2 < 128) xs[b][kk2] = e2 * inv;
            }
        }
    }
    __syncthreads();

    // ---- split-K GEMM: part[p] = xs @ W0[p*128 : p*128+128, :]
    const int kh  = tid >> 8;        // 0/1: k half
    const int sub = tid & 255;
    const int g = sub >> 5;          // 0..7 -> batches 2g, 2g+1
    const int c = sub & 31;          // float4 column group
    float4 acc0 = {0.f, 0.f, 0.f, 0.f};
    float4 acc1 = {0.f, 0.f, 0.f, 0.f};
    const float4* __restrict__ W0v =
        reinterpret_cast<const float4*>(W0 + (size_t)p * 128 * HID);

    if (p != NBLK2 - 1) {
        #pragma unroll 8
        for (int j = 0; j < 64; ++j) {
            const int kk = kh * 64 + j;
            const float4 w = W0v[kk * 32 + c];
            const float xa = xs[2 * g][kk];
            const float xb = xs[2 * g + 1][kk];
            acc0.x += xa * w.x; acc0.y += xa * w.y; acc0.z += xa * w.z; acc0.w += xa * w.w;
            acc1.x += xb * w.x; acc1.y += xb * w.y; acc1.z += xb * w.z; acc1.w += xb * w.w;
        }
    } else {
        const int klen = COMB - (NBLK2 - 1) * 128;   // 65
        const int kend = (kh * 64 + 64 < klen) ? kh * 64 + 64 : klen;
        for (int kk = kh * 64; kk < kend; ++kk) {
            const float4 w = W0v[kk * 32 + c];
            const float xa = xs[2 * g][kk];
            const float xb = xs[2 * g + 1][kk];
            acc0.x += xa * w.x; acc0.y += xa * w.y; acc0.z += xa * w.z; acc0.w += xa * w.w;
            acc1.x += xb * w.x; acc1.y += xb * w.y; acc1.z += xb * w.z; acc1.w += xb * w.w;
        }
    }

    if (kh == 1) { redA[sub] = acc0; redB[sub] = acc1; }
    __syncthreads();
    if (kh == 0) {
        const float4 oA = redA[sub], oB = redB[sub];
        acc0.x += oA.x; acc0.y += oA.y; acc0.z += oA.z; acc0.w += oA.w;
        acc1.x += oB.x; acc1.y += oB.y; acc1.z += oB.z; acc1.w += oB.w;
        float4* pp = reinterpret_cast<float4*>(part + (size_t)p * (BATCH * HID));
        pp[(2 * g) * 32 + c]     = acc0;
        pp[(2 * g + 1) * 32 + c] = acc1;
    }
}

// ---------------------------------------------------------------------------
// Kernel 3: fused partial-reduce + 4-layer ReLU MLP, batch-parallel.
// 16 blocks x 1024 threads (8 k-groups x 128 h). Constant unrolled loops.
// ---------------------------------------------------------------------------
__global__ __launch_bounds__(1024) void k_tail(const float* __restrict__ part,
                                               const float* __restrict__ b0,
                                               const float* __restrict__ Wr,
                                               const float* __restrict__ br,
                                               float* __restrict__ out) {
    const int b = blockIdx.x;
    const int tid = threadIdx.x;
    const int h = tid & 127;
    const int q = tid >> 7;            // 0..7

    __shared__ float xs[2][HID];
    __shared__ float red[8][HID];

    {
        const float* pb = part + (size_t)b * HID + h;
        float s = 0.f;
        #pragma unroll 8
        for (int j = 0; j < 32; ++j)
            s += pb[(size_t)(q * 32 + j) * (BATCH * HID)];
        if (q < 3) s += pb[(size_t)(256 + q) * (BATCH * HID)];
        red[q][h] = s;
    }
    __syncthreads();
    if (q == 0) {
        float t = ((red[0][h] + red[1][h]) + (red[2][h] + red[3][h]))
                + ((red[4][h] + red[5][h]) + (red[6][h] + red[7][h])) + b0[h];
        xs[0][h] = fmaxf(t, 0.f);
    }
    __syncthreads();

    int cur = 0;
    for (int L = 0; L < 4; ++L) {
        const float* __restrict__ W = Wr + (size_t)L * HID * HID;
        float acc = 0.f;
        #pragma unroll
        for (int j = 0; j < 16; ++j) {
            const int k = q * 16 + j;
            acc += xs[cur][k] * W[k * HID + h];
        }
        red[q][h] = acc;
        __syncthreads();
        if (q == 0) {
            float t = ((red[0][h] + red[1][h]) + (red[2][h] + red[3][h]))
                    + ((red[4][h] + red[5][h]) + (red[6][h] + red[7][h]))
                    + br[L * HID + h];
            xs[cur ^ 1][h] = fmaxf(t, 0.f);
        }
        cur ^= 1;
        __syncthreads();
    }
    if (tid < HID) out[b * HID + tid] = xs[cur][tid];
}

// ---------------------------------------------------------------------------
extern "C" void kernel_launch(void* const* d_in, const int* in_sizes, int n_in,
                              void* d_out, int out_size, void* d_ws, size_t ws_size,
                              hipStream_t stream) {
    const float* in     = (const float*)d_in[0];
    const float* WH     = (const float*)d_in[1];
    const float* WE     = (const float*)d_in[2];
    const float* a_attn = (const float*)d_in[3];
    const float* W0     = (const float*)d_in[4];
    const float* b0     = (const float*)d_in[5];
    const float* Wr     = (const float*)d_in[6];
    const float* br     = (const float*)d_in[7];
    float* out = (float*)d_out;

    float* ws   = (float*)d_ws;
    float* part = ws;                                   // 259 * 2048
    float* scal = part + (size_t)NBLK2 * (BATCH * HID); // 64

    hipLaunchKernelGGL(k_pre, dim3(BATCH), dim3(256), 0, stream,
                       in, WH, WE, a_attn, scal);
    hipLaunchKernelGGL(k_main, dim3(NBLK2), dim3(512), 0, stream,
                       in, scal, WH, W0, Wr, part);
    hipLaunchKernelGGL(k_tail, dim3(BATCH), dim3(1024), 0, stream,
                       part, b0, Wr, br, out);
}